// Round 3
// baseline (218.494 us; speedup 1.0000x reference)
//
#include <hip/hip_runtime.h>
#include <hip/hip_cooperative_groups.h>
#include <cstdint>

namespace cg = cooperative_groups;

// ---------------------------------------------------------------------------
// NeuralODE DoPri5 on MI355X — Round 8: self-validating (LSB-tagged) exchange.
// R7 post-mortem: CU-scope store ack != L2 visibility -> stamp ordering broke.
// Revert to agent-scope (sc1, R5-verified) everywhere, but remove the stamp
// protocol entirely: each published dword carries a 1-bit phase tag in the
// LSB of its low f16 (tag = (phase>>1)&1; double-buffer by phase&1 means
// successive occupants of a buffer have opposite tags). Readers poll the 7
// member partials directly until every dword's tag matches -> ONE LLC round
// trip per stage, no stamps, no exchange barriers, fully per-thread.
// ABA safety: writer's phase p-2 stores are drained (s_waitcnt vmcnt(0),
// explicit — asm stores are invisible to compiler waitcnt bookkeeping)
// before its p-1 publish; reader's p-poll follows its p-1 gather. Dword
// write atomicity makes torn 16B stores detectable per-dword.
// Accuracy: <=1 ulp on 4/8 f16 partials; own contribution uses tagged bits
// so all members sum identical values. Polls bounded (terminate, not hang).
// ---------------------------------------------------------------------------

typedef _Float16 f16x8 __attribute__((ext_vector_type(8)));
typedef float f32x4 __attribute__((ext_vector_type(4)));
typedef unsigned int u32x4 __attribute__((ext_vector_type(4)));

#define SMEM_BYTES 152640
#define SPIN_CAP 16384

// d_ws layout: [0,2MB) f16 partials (2 bufs x 256 slots x 4KB)
//   2MB+4KB: errSlots (8KB)   (stamp region retired)
#define SLOT_OFF (2u * 1024u * 1024u + 4096u)

union U64H4 { unsigned long long u; _Float16 h[4]; };

__device__ __forceinline__ float fast_tanh(float v) {
  float e = __builtin_amdgcn_exp2f(v * 2.88539008177793f);
  return fmaf(-2.0f, __builtin_amdgcn_rcpf(e + 1.0f), 1.0f);
}

extern "C" __global__ void __launch_bounds__(256, 1) neural_ode_dopri5(
    const float* __restrict__ x0g, const float* __restrict__ W1,
    const float* __restrict__ b1, const float* __restrict__ W2,
    const float* __restrict__ b2, float* __restrict__ out,
    unsigned long long* __restrict__ partB, float* __restrict__ errSlots) {
  cg::grid_group gridg = cg::this_grid();
  const int tid = threadIdx.x;
  const int bx = blockIdx.x;
  const int g = bx & 31;   // group: rows [8g, 8g+8)
  const int m = bx >> 5;   // member: hidden slice [128m, 128m+128)
  const int w = tid >> 6, lane = tid & 63, n16 = lane & 15, q = lane >> 4;
  const int r = tid >> 5, fb = tid & 31;  // thread state: row r, feats [8fb,8fb+8)

  // ---- LDS carve (dynamic, ~149 KB) --------------------------------------
  extern __shared__ char smem[];
  _Float16* W1s  = (_Float16*)smem;                  // [128 cols][264]
  _Float16* W2s  = (_Float16*)(smem + 67584);        // [256 cols][136]
  _Float16* xi_s = (_Float16*)(smem + 137216);       // [16 rows][264]; rows0-7 reused as stag
  _Float16* h_s  = (_Float16*)(smem + 145664);       // [16 rows][136]
  float* sw1t   = (float*)(smem + 150016);           // [128]
  float* sb1c   = sw1t + 128;                        // [128]
  float* sbias1 = sb1c + 128;                        // [128]
  float* sb2    = sbias1 + 128;                      // [256]
  float* sred   = sb2 + 256;                         // [4]
  float* sbc    = sred + 4;                          // [1] controller broadcast

  // ---- prologue: init tag state ------------------------------------------
  // phase p uses buf p&1 and expects tag (p>>1)&1. Phase 1 -> buf1, tag 0:
  // init buf1 LSB=1 (0x00010001). Phase 2 -> buf0, tag 1: init buf0 LSB=0.
  // Each WG re-inits its OWN slot in both bufs (covers stale cross-launch
  // data in the reused workspace), visible to all after gridg.sync().
  {
    unsigned long long* p0 = partB + (0u << 17) + (bx << 9) + (r << 6) + (fb << 1);
    unsigned long long* p1 = partB + (1u << 17) + (bx << 9) + (r << 6) + (fb << 1);
    u32x4 z0; z0[0] = z0[1] = z0[2] = z0[3] = 0u;
    u32x4 z1; z1[0] = z1[1] = z1[2] = z1[3] = 0x00010001u;
    asm volatile("global_store_dwordx4 %0, %1, off sc1" ::"v"(p0), "v"(z0)
                 : "memory");
    asm volatile("global_store_dwordx4 %0, %1, off sc1" ::"v"(p1), "v"(z1)
                 : "memory");
  }
  if (bx == 0) {
    for (int i = tid; i < 2048; i += 256)
      __hip_atomic_store(&errSlots[i], -1.0f, __ATOMIC_RELAXED,
                         __HIP_MEMORY_SCOPE_AGENT);
  }
  // stage weights into LDS
  for (int kk = 0; kk < 128; ++kk) {
    const int k = 2 * kk + (tid >> 7), c = tid & 127;
    W1s[c * 264 + k] = (_Float16)W1[k * 1024 + m * 128 + c];
  }
  for (int kk = 0; kk < 128; ++kk)
    W2s[tid * 136 + kk] = (_Float16)W2[(m * 128 + kk) * 256 + tid];
  if (tid < 128) {
    sw1t[tid] = W1[256 * 1024 + m * 128 + tid];
    sb1c[tid] = b1[m * 128 + tid];
  }
  sb2[tid] = b2[tid];
  for (int i = tid; i < 16 * 264; i += 256) xi_s[i] = (_Float16)0.0f;
  for (int i = tid; i < 16 * 136; i += 256) h_s[i] = (_Float16)0.0f;
  asm volatile("s_waitcnt vmcnt(0)" ::: "memory");  // drain asm init stores
  gridg.sync();

  // ---- per-thread ODE state ----------------------------------------------
  const float* xrow = x0g + (8 * g + r) * 256 + fb * 8;
  float x[8];
  {
    float4 v0 = ((const float4*)xrow)[0], v1 = ((const float4*)xrow)[1];
    x[0] = v0.x; x[1] = v0.y; x[2] = v0.z; x[3] = v0.w;
    x[4] = v1.x; x[5] = v1.y; x[6] = v1.z; x[7] = v1.w;
  }
  float ks[7][8];
  unsigned phase = 0;

  // ---- one vf eval: xi(8 regs/thread) -> k(8 regs/thread) ----------------
  auto stage_eval = [&](const float* xi, float ti, float* kout) {
    ++phase;
    const unsigned buf = phase & 1u;
    const unsigned tagw = (phase >> 1) & 1u;
    if (tid < 128) sbias1[tid] = fmaf(ti, sw1t[tid], sb1c[tid]);
    f16x8 xv;
#pragma unroll
    for (int j = 0; j < 8; ++j) xv[j] = (_Float16)xi[j];
    *(f16x8*)(xi_s + r * 264 + fb * 8) = xv;
    __syncthreads();

    // GEMM1: h_pre[16][128] = xi @ W1slice + bias1
    f32x4 acc1[2];
#pragma unroll
    for (int tt = 0; tt < 2; ++tt) {
      const float bb = sbias1[(2 * w + tt) * 16 + n16];
      acc1[tt] = (f32x4){bb, bb, bb, bb};
    }
#pragma unroll
    for (int kk = 0; kk < 8; ++kk) {
      const f16x8 av = *(const f16x8*)(xi_s + n16 * 264 + kk * 32 + q * 8);
#pragma unroll
      for (int tt = 0; tt < 2; ++tt) {
        const f16x8 bv =
            *(const f16x8*)(W1s + ((2 * w + tt) * 16 + n16) * 264 + kk * 32 + q * 8);
        acc1[tt] = __builtin_amdgcn_mfma_f32_16x16x32_f16(av, bv, acc1[tt], 0, 0, 0);
      }
    }
#pragma unroll
    for (int tt = 0; tt < 2; ++tt) {
      const int c = (2 * w + tt) * 16 + n16;
#pragma unroll
      for (int reg = 0; reg < 4; ++reg)
        h_s[(q * 4 + reg) * 136 + c] = (_Float16)fast_tanh(acc1[tt][reg]);
    }
    __syncthreads();

    // GEMM2 partial: kp[16][256] = h @ W2slice (bias added by reader)
    f32x4 acc2[4];
#pragma unroll
    for (int tt = 0; tt < 4; ++tt) acc2[tt] = (f32x4){0.f, 0.f, 0.f, 0.f};
#pragma unroll
    for (int kk = 0; kk < 4; ++kk) {
      const f16x8 av = *(const f16x8*)(h_s + n16 * 136 + kk * 32 + q * 8);
#pragma unroll
      for (int tt = 0; tt < 4; ++tt) {
        const f16x8 bv =
            *(const f16x8*)(W2s + ((w * 4 + tt) * 16 + n16) * 136 + kk * 32 + q * 8);
        acc2[tt] = __builtin_amdgcn_mfma_f32_16x16x32_f16(av, bv, acc2[tt], 0, 0, 0);
      }
    }
    // transpose fragments -> row-major f16 staging in LDS (reuse xi_s rows0-7)
    _Float16* stag = xi_s;
    if (q < 2) {
#pragma unroll
      for (int tt = 0; tt < 4; ++tt) {
        const int c = (w * 4 + tt) * 16 + n16;
#pragma unroll
        for (int reg = 0; reg < 4; ++reg)
          stag[(q * 4 + reg) * 264 + c] = (_Float16)acc2[tt][reg];
      }
    }
    __syncthreads();

    // publish: 16 B per thread, sc1 (LLC), LSB of each dword's low f16 = tag.
    // Explicit drain first: orders this thread's phase p-2 stores (and old
    // poll loads) at the LLC before this publish — the ABA guard.
    asm volatile("s_waitcnt vmcnt(0)" ::: "memory");
    unsigned long long u0, u1;
    {
      const unsigned long long* srcp =
          (const unsigned long long*)(stag + r * 264 + fb * 8);
      unsigned long long a = srcp[0], b = srcp[1];
      const unsigned long long M = 0x0000000100000001ULL;
      a = (a & ~M) | (tagw ? M : 0ULL);
      b = (b & ~M) | (tagw ? M : 0ULL);
      u0 = a; u1 = b;  // own contribution uses the SAME tagged bits
      u32x4 d;
      d[0] = (unsigned)a; d[1] = (unsigned)(a >> 32);
      d[2] = (unsigned)b; d[3] = (unsigned)(b >> 32);
      unsigned long long* dst =
          partB + (buf << 17) + (bx << 9) + (r << 6) + (fb << 1);
      asm volatile("global_store_dwordx4 %0, %1, off sc1" ::"v"(dst), "v"(d)
                   : "memory");
    }

    // gather: per-thread poll of the 7 other members' 16B until every dword's
    // tag matches. One coherence RT per retry; no barriers, no stamps.
    const int gbase = (buf << 17) + (r << 6) + (fb << 1);
    u32x4 rr[8];
    {
      int spin = 0;
      for (;;) {
#pragma unroll
        for (int mm = 0; mm < 8; ++mm) {
          if (mm == m) continue;
          const unsigned long long* pp = partB + gbase + ((mm * 32 + g) << 9);
          asm volatile("global_load_dwordx4 %0, %1, off sc1"
                       : "=&v"(rr[mm])
                       : "v"(pp)
                       : "memory");
        }
        asm volatile("s_waitcnt vmcnt(0)" ::: "memory");
        __builtin_amdgcn_sched_barrier(0);
        unsigned bad = 0;
#pragma unroll
        for (int mm = 0; mm < 8; ++mm) {
          if (mm == m) continue;
          bad |= (rr[mm][0] ^ tagw) | (rr[mm][1] ^ tagw) |
                 (rr[mm][2] ^ tagw) | (rr[mm][3] ^ tagw);
        }
        bad &= 1u;
        if (__all(bad == 0) || ++spin > SPIN_CAP) break;
      }
    }
    // sum: b2 + own (tagged, from registers) + 7 gathered
    float kacc[8];
    {
      const float4* sb2v = (const float4*)(sb2 + fb * 8);
      float4 bA = sb2v[0], bB = sb2v[1];
      U64H4 oa, ob; oa.u = u0; ob.u = u1;
      kacc[0] = bA.x + (float)oa.h[0]; kacc[1] = bA.y + (float)oa.h[1];
      kacc[2] = bA.z + (float)oa.h[2]; kacc[3] = bA.w + (float)oa.h[3];
      kacc[4] = bB.x + (float)ob.h[0]; kacc[5] = bB.y + (float)ob.h[1];
      kacc[6] = bB.z + (float)ob.h[2]; kacc[7] = bB.w + (float)ob.h[3];
    }
#pragma unroll
    for (int mm = 0; mm < 8; ++mm) {
      if (mm == m) continue;
      U64H4 ua, ub;
      ua.u = ((unsigned long long)rr[mm][1] << 32) |
             (unsigned long long)rr[mm][0];
      ub.u = ((unsigned long long)rr[mm][3] << 32) |
             (unsigned long long)rr[mm][2];
#pragma unroll
      for (int j = 0; j < 4; ++j) {
        kacc[j] += (float)ua.h[j];
        kacc[4 + j] += (float)ub.h[j];
      }
    }
#pragma unroll
    for (int j = 0; j < 8; ++j) kout[j] = kacc[j];
  };

  // ---- Butcher tableau ----------------------------------------------------
  const float AB[6][6] = {
      {(float)(1.0 / 5.0), 0, 0, 0, 0, 0},
      {(float)(3.0 / 40.0), (float)(9.0 / 40.0), 0, 0, 0, 0},
      {(float)(44.0 / 45.0), (float)(-56.0 / 15.0), (float)(32.0 / 9.0), 0, 0, 0},
      {(float)(19372.0 / 6561.0), (float)(-25360.0 / 2187.0),
       (float)(64448.0 / 6561.0), (float)(-212.0 / 729.0), 0, 0},
      {(float)(9017.0 / 3168.0), (float)(-355.0 / 33.0),
       (float)(46732.0 / 5247.0), (float)(49.0 / 176.0),
       (float)(-5103.0 / 18656.0), 0},
      {(float)(35.0 / 384.0), 0.0f, (float)(500.0 / 1113.0),
       (float)(125.0 / 192.0), (float)(-2187.0 / 6784.0), (float)(11.0 / 84.0)}};
  const float CC[7] = {0.0f, (float)(1.0 / 5.0), (float)(3.0 / 10.0),
                       (float)(4.0 / 5.0), (float)(8.0 / 9.0), 1.0f, 1.0f};
  const float DD[7] = {(float)(35.0 / 384.0 - 5179.0 / 57600.0), 0.0f,
                       (float)(500.0 / 1113.0 - 7571.0 / 16695.0),
                       (float)(125.0 / 192.0 - 393.0 / 640.0),
                       (float)(-2187.0 / 6784.0 + 92097.0 / 339200.0),
                       (float)(11.0 / 84.0 - 187.0 / 2100.0),
                       (float)(-1.0 / 40.0)};

  float t = 0.0f, dt = 0.05f;
  stage_eval(x, 0.0f, ks[0]);  // FSAL seed

  for (int it = 0; it < 64; ++it) {
    if (t >= 1.0f) break;  // controller is globally uniform -> exact
    const float dt_c = fmaxf(fminf(dt, 1.0f - t), 0.0f);

    float x5[8];
#pragma unroll
    for (int s = 1; s <= 6; ++s) {
      float xi[8];
#pragma unroll
      for (int j = 0; j < 8; ++j) {
        float v = x[j];
#pragma unroll
        for (int p = 0; p < 6; ++p)
          if (p < s) v = fmaf(dt_c * AB[s - 1][p], ks[p][j], v);
        xi[j] = v;
        if (s == 6) x5[j] = v;  // stage-7 point == x5 (FSAL)
      }
      stage_eval(xi, fmaf(CC[s], dt_c, t), ks[s]);
    }

    // member 0 of each group publishes its group's err sum to a slot
    if (m == 0) {
      float loc = 0.0f;
#pragma unroll
      for (int j = 0; j < 8; ++j) {
        float e = 0.0f;
#pragma unroll
        for (int s = 0; s < 7; ++s) e = fmaf(dt_c * DD[s], ks[s][j], e);
        const float scale = fmaf(1e-3f, fmaxf(fabsf(x[j]), fabsf(x5[j])), 1e-4f);
        const float rr2 = e / scale;
        loc = fmaf(rr2, rr2, loc);
      }
#pragma unroll
      for (int o = 32; o > 0; o >>= 1) loc += __shfl_down(loc, o);
      if (lane == 0) sred[w] = loc;
      __syncthreads();
      if (tid == 0) {
        const float s4 = sred[0] + sred[1] + sred[2] + sred[3];
        __hip_atomic_store(&errSlots[it * 32 + g], s4, __ATOMIC_RELAXED,
                           __HIP_MEMORY_SCOPE_AGENT);
      }
    }
    // wave 0 polls the 32 slots (sentinel: init values negative), bounded
    if (w == 0) {
      int spin = 0;
      for (;;) {
        float v = 0.0f;
        bool okl = true;
        if (lane < 32) {
          v = __hip_atomic_load(&errSlots[it * 32 + lane], __ATOMIC_RELAXED,
                                __HIP_MEMORY_SCOPE_AGENT);
          okl = (v >= 0.0f);
        }
        if (__all(okl)) {
#pragma unroll
          for (int o = 32; o > 0; o >>= 1) v += __shfl_down(v, o);
          if (lane == 0) sbc[0] = v;
          break;
        }
        if (++spin > SPIN_CAP) {
          if (lane == 0) sbc[0] = 0.0f;
          break;
        }
      }
    }
    __syncthreads();
    const float total = sbc[0];
    const float err_norm = sqrtf(total * (1.0f / 65536.0f));
    const bool accept = err_norm <= 1.0f;
    float factor = 0.9f * powf(err_norm + 1e-10f, -0.2f);
    factor = fminf(fmaxf(factor, 0.2f), 5.0f);
    if (accept) {
      t = t + dt_c;
#pragma unroll
      for (int j = 0; j < 8; ++j) { x[j] = x5[j]; ks[0][j] = ks[6][j]; }
    }
    dt = dt_c * factor;
  }

  // ---- output: stack([x0, xf]) (member 0 only) ---------------------------
  if (m == 0) {
    float4* o0 = (float4*)(out + (8 * g + r) * 256 + fb * 8);
    const float4* xr = (const float4*)xrow;
    o0[0] = xr[0]; o0[1] = xr[1];
    float4 a0, a1;
    a0.x = x[0]; a0.y = x[1]; a0.z = x[2]; a0.w = x[3];
    a1.x = x[4]; a1.y = x[5]; a1.z = x[6]; a1.w = x[7];
    float4* o1 = (float4*)(out + 65536 + (8 * g + r) * 256 + fb * 8);
    o1[0] = a0; o1[1] = a1;
  }
}

extern "C" void kernel_launch(void* const* d_in, const int* in_sizes, int n_in,
                              void* d_out, int out_size, void* d_ws,
                              size_t ws_size, hipStream_t stream) {
  const float* x0 = (const float*)d_in[0];
  const float* W1 = (const float*)d_in[1];
  const float* b1 = (const float*)d_in[2];
  const float* W2 = (const float*)d_in[3];
  const float* b2 = (const float*)d_in[4];
  float* out = (float*)d_out;
  char* ws = (char*)d_ws;
  unsigned long long* partB = (unsigned long long*)ws;
  float* errSlots = (float*)(ws + SLOT_OFF);

  hipFuncSetAttribute((const void*)neural_ode_dopri5,
                      hipFuncAttributeMaxDynamicSharedMemorySize, SMEM_BYTES);

  void* args[] = {&x0, &W1, &b1, &W2, &b2, &out, &partB, &errSlots};
  hipLaunchCooperativeKernel((void*)neural_ode_dopri5, dim3(256), dim3(256),
                             args, SMEM_BYTES, stream);
}

// Round 6
// 217.727 us; speedup vs baseline: 1.0035x; 1.0035x over previous
//
#include <hip/hip_runtime.h>
#include <hip/hip_cooperative_groups.h>
#include <cstdint>

namespace cg = cooperative_groups;

// ---------------------------------------------------------------------------
// NeuralODE DoPri5 on MI355X — Round 11: tagged exchange + per-wave sentinels.
// R9/R10 post-mortem: sc[1:0] is a SCOPE field (0=CU, sc0=WG, sc1=agent,
// sc0sc1=system); sc0 loads are WG-scope and can hit the reader's own stale
// L1 forever -> both XCD-local variants spun out. No ISA encoding exists for
// XCD-L2 scope -> idea buried. This round recombines the two VERIFIED LLC
// protocols: R8's per-dword phase tags (publish needs no drain/stamp; ABA
// guarded by each thread's own vmcnt chain) + R5's cheap-poll insight.
// New: each WAVE polls 7 sentinel dwords (member j's first dword of this
// wave's 128-u64 span — part of the payload itself, so its tag flip
// coincides with data arrival), then issues the full gather ONCE; the
// gather's per-dword tag check (R8-verified) remains the correctness
// authority, so sentinels are a congestion optimization only. No barriers
// in the exchange. All polls bounded.
// ---------------------------------------------------------------------------

typedef _Float16 f16x8 __attribute__((ext_vector_type(8)));
typedef float f32x4 __attribute__((ext_vector_type(4)));
typedef unsigned int u32x4 __attribute__((ext_vector_type(4)));

#define SMEM_BYTES 152640
#define SPIN_CAP 16384

// d_ws layout: [0,2MB) f16 partials (2 bufs x 256 slots x 4KB)
//   2MB+4KB: errSlots (8KB)
#define SLOT_OFF (2u * 1024u * 1024u + 4096u)

union U64H4 { unsigned long long u; _Float16 h[4]; };

__device__ __forceinline__ float fast_tanh(float v) {
  float e = __builtin_amdgcn_exp2f(v * 2.88539008177793f);
  return fmaf(-2.0f, __builtin_amdgcn_rcpf(e + 1.0f), 1.0f);
}

extern "C" __global__ void __launch_bounds__(256, 1) neural_ode_dopri5(
    const float* __restrict__ x0g, const float* __restrict__ W1,
    const float* __restrict__ b1, const float* __restrict__ W2,
    const float* __restrict__ b2, float* __restrict__ out,
    unsigned long long* __restrict__ partB, float* __restrict__ errSlots) {
  cg::grid_group gridg = cg::this_grid();
  const int tid = threadIdx.x;
  const int bx = blockIdx.x;
  const int g = bx & 31;   // group: rows [8g, 8g+8)
  const int m = bx >> 5;   // member: hidden slice [128m, 128m+128)
  const int w = tid >> 6, lane = tid & 63, n16 = lane & 15, q = lane >> 4;
  const int r = tid >> 5, fb = tid & 31;  // thread state: row r, feats [8fb,8fb+8)

  // ---- LDS carve (dynamic, ~149 KB) --------------------------------------
  extern __shared__ char smem[];
  _Float16* W1s  = (_Float16*)smem;                  // [128 cols][264]
  _Float16* W2s  = (_Float16*)(smem + 67584);        // [256 cols][136]
  _Float16* xi_s = (_Float16*)(smem + 137216);       // [16 rows][264]; rows0-7 reused as stag
  _Float16* h_s  = (_Float16*)(smem + 145664);       // [16 rows][136]
  float* sw1t   = (float*)(smem + 150016);           // [128]
  float* sb1c   = sw1t + 128;                        // [128]
  float* sbias1 = sb1c + 128;                        // [128]
  float* sb2    = sbias1 + 128;                      // [256]
  float* sred   = sb2 + 256;                         // [4]
  float* sbc    = sred + 4;                          // [1] controller broadcast

  // ---- prologue: init tag state ------------------------------------------
  // phase p uses buf p&1, expects tag (p>>1)&1. Phase1->buf1 tag0: init buf1
  // LSB=1 (0x00010001). Phase2->buf0 tag1: init buf0 LSB=0. Each WG inits its
  // own slot in both bufs; visible to all after gridg.sync().
  {
    unsigned long long* p0 = partB + (0u << 17) + (bx << 9) + (r << 6) + (fb << 1);
    unsigned long long* p1 = partB + (1u << 17) + (bx << 9) + (r << 6) + (fb << 1);
    u32x4 z0; z0[0] = z0[1] = z0[2] = z0[3] = 0u;
    u32x4 z1; z1[0] = z1[1] = z1[2] = z1[3] = 0x00010001u;
    asm volatile("global_store_dwordx4 %0, %1, off sc1" ::"v"(p0), "v"(z0)
                 : "memory");
    asm volatile("global_store_dwordx4 %0, %1, off sc1" ::"v"(p1), "v"(z1)
                 : "memory");
  }
  if (bx == 0) {
    for (int i = tid; i < 2048; i += 256)
      __hip_atomic_store(&errSlots[i], -1.0f, __ATOMIC_RELAXED,
                         __HIP_MEMORY_SCOPE_AGENT);
  }
  // stage weights into LDS
  for (int kk = 0; kk < 128; ++kk) {
    const int k = 2 * kk + (tid >> 7), c = tid & 127;
    W1s[c * 264 + k] = (_Float16)W1[k * 1024 + m * 128 + c];
  }
  for (int kk = 0; kk < 128; ++kk)
    W2s[tid * 136 + kk] = (_Float16)W2[(m * 128 + kk) * 256 + tid];
  if (tid < 128) {
    sw1t[tid] = W1[256 * 1024 + m * 128 + tid];
    sb1c[tid] = b1[m * 128 + tid];
  }
  sb2[tid] = b2[tid];
  for (int i = tid; i < 16 * 264; i += 256) xi_s[i] = (_Float16)0.0f;
  for (int i = tid; i < 16 * 136; i += 256) h_s[i] = (_Float16)0.0f;
  asm volatile("s_waitcnt vmcnt(0)" ::: "memory");  // drain asm init stores
  gridg.sync();

  // ---- per-thread ODE state ----------------------------------------------
  const float* xrow = x0g + (8 * g + r) * 256 + fb * 8;
  float x[8];
  {
    float4 v0 = ((const float4*)xrow)[0], v1 = ((const float4*)xrow)[1];
    x[0] = v0.x; x[1] = v0.y; x[2] = v0.z; x[3] = v0.w;
    x[4] = v1.x; x[5] = v1.y; x[6] = v1.z; x[7] = v1.w;
  }
  float ks[7][8];
  unsigned phase = 0;

  // ---- one vf eval: xi(8 regs/thread) -> k(8 regs/thread) ----------------
  auto stage_eval = [&](const float* xi, float ti, float* kout) {
    ++phase;
    const unsigned buf = phase & 1u;
    const unsigned tagw = (phase >> 1) & 1u;
    if (tid < 128) sbias1[tid] = fmaf(ti, sw1t[tid], sb1c[tid]);
    f16x8 xv;
#pragma unroll
    for (int j = 0; j < 8; ++j) xv[j] = (_Float16)xi[j];
    *(f16x8*)(xi_s + r * 264 + fb * 8) = xv;
    __syncthreads();

    // GEMM1: h_pre[16][128] = xi @ W1slice + bias1
    f32x4 acc1[2];
#pragma unroll
    for (int tt = 0; tt < 2; ++tt) {
      const float bb = sbias1[(2 * w + tt) * 16 + n16];
      acc1[tt] = (f32x4){bb, bb, bb, bb};
    }
#pragma unroll
    for (int kk = 0; kk < 8; ++kk) {
      const f16x8 av = *(const f16x8*)(xi_s + n16 * 264 + kk * 32 + q * 8);
#pragma unroll
      for (int tt = 0; tt < 2; ++tt) {
        const f16x8 bv =
            *(const f16x8*)(W1s + ((2 * w + tt) * 16 + n16) * 264 + kk * 32 + q * 8);
        acc1[tt] = __builtin_amdgcn_mfma_f32_16x16x32_f16(av, bv, acc1[tt], 0, 0, 0);
      }
    }
#pragma unroll
    for (int tt = 0; tt < 2; ++tt) {
      const int c = (2 * w + tt) * 16 + n16;
#pragma unroll
      for (int reg = 0; reg < 4; ++reg)
        h_s[(q * 4 + reg) * 136 + c] = (_Float16)fast_tanh(acc1[tt][reg]);
    }
    __syncthreads();

    // GEMM2 partial: kp[16][256] = h @ W2slice (bias added by reader)
    f32x4 acc2[4];
#pragma unroll
    for (int tt = 0; tt < 4; ++tt) acc2[tt] = (f32x4){0.f, 0.f, 0.f, 0.f};
#pragma unroll
    for (int kk = 0; kk < 4; ++kk) {
      const f16x8 av = *(const f16x8*)(h_s + n16 * 136 + kk * 32 + q * 8);
#pragma unroll
      for (int tt = 0; tt < 4; ++tt) {
        const f16x8 bv =
            *(const f16x8*)(W2s + ((w * 4 + tt) * 16 + n16) * 136 + kk * 32 + q * 8);
        acc2[tt] = __builtin_amdgcn_mfma_f32_16x16x32_f16(av, bv, acc2[tt], 0, 0, 0);
      }
    }
    // transpose fragments -> row-major f16 staging in LDS (reuse xi_s rows0-7)
    _Float16* stag = xi_s;
    if (q < 2) {
#pragma unroll
      for (int tt = 0; tt < 4; ++tt) {
        const int c = (w * 4 + tt) * 16 + n16;
#pragma unroll
        for (int reg = 0; reg < 4; ++reg)
          stag[(q * 4 + reg) * 264 + c] = (_Float16)acc2[tt][reg];
      }
    }
    __syncthreads();

    // publish: 16 B per thread, sc1 (LLC), LSB of each dword's low f16 = tag.
    // Pre-drain is the ABA belt-and-braces (asm stores are invisible to
    // compiler waitcnt bookkeeping); near-free here since prior gather loads
    // already completed.
    asm volatile("s_waitcnt vmcnt(0)" ::: "memory");
    unsigned long long u0, u1;
    {
      const unsigned long long* srcp =
          (const unsigned long long*)(stag + r * 264 + fb * 8);
      unsigned long long a = srcp[0], b = srcp[1];
      const unsigned long long M = 0x0000000100000001ULL;
      a = (a & ~M) | (tagw ? M : 0ULL);
      b = (b & ~M) | (tagw ? M : 0ULL);
      u0 = a; u1 = b;  // own contribution uses the SAME tagged bits
      u32x4 d;
      d[0] = (unsigned)a; d[1] = (unsigned)(a >> 32);
      d[2] = (unsigned)b; d[3] = (unsigned)(b >> 32);
      unsigned long long* dst =
          partB + (buf << 17) + (bx << 9) + (r << 6) + (fb << 1);
      asm volatile("global_store_dwordx4 %0, %1, off sc1" ::"v"(dst), "v"(d)
                   : "memory");
    }

    // per-wave sentinel pre-poll: lane j<8 (j!=m) watches dword0 of member
    // j's FIRST u64 in this wave's 128-u64 span. The sentinel is part of the
    // payload, so its tag flip coincides with that member's data landing at
    // the LLC. 7 dwords/wave per retry — negligible LLC traffic (vs R8's
    // 7x16B per THREAD per retry, which congested the LLC). Optimization
    // only: the gather below re-verifies every dword.
    {
      const int j = lane & 7;
      const unsigned* sp =
          (const unsigned*)(partB + (buf << 17) + (((j << 5) + g) << 9) +
                            (w << 7));
      const bool active = (lane < 8) && (j != m);
      int spin = 0;
      for (;;) {
        unsigned vv = tagw;
        if (active)
          asm volatile("global_load_dword %0, %1, off sc1\n\t"
                       "s_waitcnt vmcnt(0)"
                       : "=v"(vv)
                       : "v"(sp)
                       : "memory");
        if (__all((vv & 1u) == tagw) || ++spin > SPIN_CAP) break;
      }
    }

    // gather: 7 members' 16B with per-dword tag verification (correctness
    // authority; R8-verified). Expected clean on first pass after sentinels.
    const int gbase = (buf << 17) + (r << 6) + (fb << 1);
    u32x4 rr[8];
    {
      int spin = 0;
      for (;;) {
#pragma unroll
        for (int mm = 0; mm < 8; ++mm) {
          if (mm == m) continue;
          const unsigned long long* pp = partB + gbase + ((mm * 32 + g) << 9);
          asm volatile("global_load_dwordx4 %0, %1, off sc1"
                       : "=&v"(rr[mm])
                       : "v"(pp)
                       : "memory");
        }
        asm volatile("s_waitcnt vmcnt(0)" ::: "memory");
        __builtin_amdgcn_sched_barrier(0);
        unsigned bad = 0;
#pragma unroll
        for (int mm = 0; mm < 8; ++mm) {
          if (mm == m) continue;
          bad |= (rr[mm][0] ^ tagw) | (rr[mm][1] ^ tagw) |
                 (rr[mm][2] ^ tagw) | (rr[mm][3] ^ tagw);
        }
        bad &= 1u;
        if (__all(bad == 0) || ++spin > SPIN_CAP) break;
      }
    }
    // sum: b2 + own (tagged, from registers) + 7 gathered
    float kacc[8];
    {
      const float4* sb2v = (const float4*)(sb2 + fb * 8);
      float4 bA = sb2v[0], bB = sb2v[1];
      U64H4 oa, ob; oa.u = u0; ob.u = u1;
      kacc[0] = bA.x + (float)oa.h[0]; kacc[1] = bA.y + (float)oa.h[1];
      kacc[2] = bA.z + (float)oa.h[2]; kacc[3] = bA.w + (float)oa.h[3];
      kacc[4] = bB.x + (float)ob.h[0]; kacc[5] = bB.y + (float)ob.h[1];
      kacc[6] = bB.z + (float)ob.h[2]; kacc[7] = bB.w + (float)ob.h[3];
    }
#pragma unroll
    for (int mm = 0; mm < 8; ++mm) {
      if (mm == m) continue;
      U64H4 ua, ub;
      ua.u = ((unsigned long long)rr[mm][1] << 32) |
             (unsigned long long)rr[mm][0];
      ub.u = ((unsigned long long)rr[mm][3] << 32) |
             (unsigned long long)rr[mm][2];
#pragma unroll
      for (int j = 0; j < 4; ++j) {
        kacc[j] += (float)ua.h[j];
        kacc[4 + j] += (float)ub.h[j];
      }
    }
#pragma unroll
    for (int j = 0; j < 8; ++j) kout[j] = kacc[j];
  };

  // ---- Butcher tableau ----------------------------------------------------
  const float AB[6][6] = {
      {(float)(1.0 / 5.0), 0, 0, 0, 0, 0},
      {(float)(3.0 / 40.0), (float)(9.0 / 40.0), 0, 0, 0, 0},
      {(float)(44.0 / 45.0), (float)(-56.0 / 15.0), (float)(32.0 / 9.0), 0, 0, 0},
      {(float)(19372.0 / 6561.0), (float)(-25360.0 / 2187.0),
       (float)(64448.0 / 6561.0), (float)(-212.0 / 729.0), 0, 0},
      {(float)(9017.0 / 3168.0), (float)(-355.0 / 33.0),
       (float)(46732.0 / 5247.0), (float)(49.0 / 176.0),
       (float)(-5103.0 / 18656.0), 0},
      {(float)(35.0 / 384.0), 0.0f, (float)(500.0 / 1113.0),
       (float)(125.0 / 192.0), (float)(-2187.0 / 6784.0), (float)(11.0 / 84.0)}};
  const float CC[7] = {0.0f, (float)(1.0 / 5.0), (float)(3.0 / 10.0),
                       (float)(4.0 / 5.0), (float)(8.0 / 9.0), 1.0f, 1.0f};
  const float DD[7] = {(float)(35.0 / 384.0 - 5179.0 / 57600.0), 0.0f,
                       (float)(500.0 / 1113.0 - 7571.0 / 16695.0),
                       (float)(125.0 / 192.0 - 393.0 / 640.0),
                       (float)(-2187.0 / 6784.0 + 92097.0 / 339200.0),
                       (float)(11.0 / 84.0 - 187.0 / 2100.0),
                       (float)(-1.0 / 40.0)};

  float t = 0.0f, dt = 0.05f;
  stage_eval(x, 0.0f, ks[0]);  // FSAL seed

  for (int it = 0; it < 64; ++it) {
    if (t >= 1.0f) break;  // controller is globally uniform -> exact
    const float dt_c = fmaxf(fminf(dt, 1.0f - t), 0.0f);

    float x5[8];
#pragma unroll
    for (int s = 1; s <= 6; ++s) {
      float xi[8];
#pragma unroll
      for (int j = 0; j < 8; ++j) {
        float v = x[j];
#pragma unroll
        for (int p = 0; p < 6; ++p)
          if (p < s) v = fmaf(dt_c * AB[s - 1][p], ks[p][j], v);
        xi[j] = v;
        if (s == 6) x5[j] = v;  // stage-7 point == x5 (FSAL)
      }
      stage_eval(xi, fmaf(CC[s], dt_c, t), ks[s]);
    }

    // member 0 of each group publishes its group's err sum to a slot
    if (m == 0) {
      float loc = 0.0f;
#pragma unroll
      for (int j = 0; j < 8; ++j) {
        float e = 0.0f;
#pragma unroll
        for (int s = 0; s < 7; ++s) e = fmaf(dt_c * DD[s], ks[s][j], e);
        const float scale = fmaf(1e-3f, fmaxf(fabsf(x[j]), fabsf(x5[j])), 1e-4f);
        const float rr2 = e / scale;
        loc = fmaf(rr2, rr2, loc);
      }
#pragma unroll
      for (int o = 32; o > 0; o >>= 1) loc += __shfl_down(loc, o);
      if (lane == 0) sred[w] = loc;
      __syncthreads();
      if (tid == 0) {
        const float s4 = sred[0] + sred[1] + sred[2] + sred[3];
        __hip_atomic_store(&errSlots[it * 32 + g], s4, __ATOMIC_RELAXED,
                           __HIP_MEMORY_SCOPE_AGENT);
      }
    }
    // wave 0 polls the 32 slots (sentinel: init values negative), bounded
    if (w == 0) {
      int spin = 0;
      for (;;) {
        float v = 0.0f;
        bool okl = true;
        if (lane < 32) {
          v = __hip_atomic_load(&errSlots[it * 32 + lane], __ATOMIC_RELAXED,
                                __HIP_MEMORY_SCOPE_AGENT);
          okl = (v >= 0.0f);
        }
        if (__all(okl)) {
#pragma unroll
          for (int o = 32; o > 0; o >>= 1) v += __shfl_down(v, o);
          if (lane == 0) sbc[0] = v;
          break;
        }
        if (++spin > SPIN_CAP) {
          if (lane == 0) sbc[0] = 0.0f;
          break;
        }
      }
    }
    __syncthreads();
    const float total = sbc[0];
    const float err_norm = sqrtf(total * (1.0f / 65536.0f));
    const bool accept = err_norm <= 1.0f;
    float factor = 0.9f * powf(err_norm + 1e-10f, -0.2f);
    factor = fminf(fmaxf(factor, 0.2f), 5.0f);
    if (accept) {
      t = t + dt_c;
#pragma unroll
      for (int j = 0; j < 8; ++j) { x[j] = x5[j]; ks[0][j] = ks[6][j]; }
    }
    dt = dt_c * factor;
  }

  // ---- output: stack([x0, xf]) (member 0 only) ---------------------------
  if (m == 0) {
    float4* o0 = (float4*)(out + (8 * g + r) * 256 + fb * 8);
    const float4* xr = (const float4*)xrow;
    o0[0] = xr[0]; o0[1] = xr[1];
    float4 a0, a1;
    a0.x = x[0]; a0.y = x[1]; a0.z = x[2]; a0.w = x[3];
    a1.x = x[4]; a1.y = x[5]; a1.z = x[6]; a1.w = x[7];
    float4* o1 = (float4*)(out + 65536 + (8 * g + r) * 256 + fb * 8);
    o1[0] = a0; o1[1] = a1;
  }
}

extern "C" void kernel_launch(void* const* d_in, const int* in_sizes, int n_in,
                              void* d_out, int out_size, void* d_ws,
                              size_t ws_size, hipStream_t stream) {
  const float* x0 = (const float*)d_in[0];
  const float* W1 = (const float*)d_in[1];
  const float* b1 = (const float*)d_in[2];
  const float* W2 = (const float*)d_in[3];
  const float* b2 = (const float*)d_in[4];
  float* out = (float*)d_out;
  char* ws = (char*)d_ws;
  unsigned long long* partB = (unsigned long long*)ws;
  float* errSlots = (float*)(ws + SLOT_OFF);

  hipFuncSetAttribute((const void*)neural_ode_dopri5,
                      hipFuncAttributeMaxDynamicSharedMemorySize, SMEM_BYTES);

  void* args[] = {&x0, &W1, &b1, &W2, &b2, &out, &partB, &errSlots};
  hipLaunchCooperativeKernel((void*)neural_ode_dopri5, dim3(256), dim3(256),
                             args, SMEM_BYTES, stream);
}